// Round 6
// baseline (419.047 us; speedup 1.0000x reference)
//
#include <hip/hip_runtime.h>

// Problem geometry (fixed by setup_inputs)
#define BB 32
#define DD 64
#define HWSZ 4096                  // H*W
#define KK 1024
#define NPIX (BB*HWSZ)             // 131072
#define NELEM (NPIX*DD)            // 8388608

// Output layout (concatenated float32)
#define IDX_OUT_OFF NELEM
#define LOSS_OFF (IDX_OUT_OFF + NPIX)

// Workspace layout (bytes)
#define WS_E2    0                       // 4 KB
#define WS_EBH   (WS_E2 + 4096)          // 128 KB  (B-frags hi)
#define WS_EBL   (WS_EBH + 131072)       // 128 KB  (B-frags lo)
#define WS_IDX   (WS_EBL + 131072)       // 512 KB
#define WS_LIST  (WS_IDX + NPIX*4)       // 512 KB
#define WS_CNT   (WS_LIST + NPIX*4)      // 64 B
#define WS_PART  (WS_CNT + 64)           // 4 KB

// Ambiguity band: worst-case |fast-score - fp32-ref-score| diff ~2.4e-5; 6x margin.
#define BAND 1.5e-4f

typedef __attribute__((ext_vector_type(8))) short short8v;
typedef __attribute__((ext_vector_type(4))) float float4v;

__device__ __forceinline__ unsigned short bf16_rne(float f) {
    unsigned u = __float_as_uint(f);
    u += 0x7fffu + ((u >> 16) & 1u);
    return (unsigned short)(u >> 16);
}
__device__ __forceinline__ float bf16_tof(unsigned short h) {
    return __uint_as_float(((unsigned)h) << 16);
}

// numpy-style fp32 sum of 64 squares (squares rounded separately; no FMA).
__device__ __forceinline__ float np_sumsq64(const float* a) {
#pragma clang fp contract(off)
    float r0=0.f,r1=0.f,r2=0.f,r3=0.f,r4=0.f,r5=0.f,r6=0.f,r7=0.f;
#pragma unroll
    for (int i = 0; i < 64; i += 8) {
        r0 += a[i+0]*a[i+0]; r1 += a[i+1]*a[i+1];
        r2 += a[i+2]*a[i+2]; r3 += a[i+3]*a[i+3];
        r4 += a[i+4]*a[i+4]; r5 += a[i+5]*a[i+5];
        r6 += a[i+6]*a[i+6]; r7 += a[i+7]*a[i+7];
    }
    return ((r0+r1)+(r2+r3))+((r4+r5)+(r6+r7));
}

// ---------------------------------------------------------------------------
// e2[k] = fp32 sum of squares of codebook row k (numpy separate-square bits).
__global__ __launch_bounds__(256) void vq_e2(const float* __restrict__ emb,
                                             float* __restrict__ e2) {
    int k = blockIdx.x * blockDim.x + threadIdx.x;
    float ek[DD];
    const float4* p = reinterpret_cast<const float4*>(emb + (size_t)k * DD);
#pragma unroll
    for (int q = 0; q < 16; ++q) {
        float4 v = p[q];
        ek[4*q+0]=v.x; ek[4*q+1]=v.y; ek[4*q+2]=v.z; ek[4*q+3]=v.w;
    }
    e2[k] = np_sumsq64(ek);
}

// ---------------------------------------------------------------------------
// Build MFMA B-fragments of the hi/lo bf16 split of emb^T.
// slot = ct*2+ks (128 slots); lane l holds col = ct*16+(l&15),
// k-elements d = ks*32 + (l>>4)*8 + j  (bijective fill; matches A fill).
__global__ __launch_bounds__(256) void vq_bfrag(const float* __restrict__ emb,
                                                short* __restrict__ ebh,
                                                short* __restrict__ ebl) {
    int t    = blockIdx.x * 256 + threadIdx.x;   // 8192 = 128 slots * 64 lanes
    int l    = t & 63;
    int slot = t >> 6;
    int ct = slot >> 1, ks = slot & 1;
    int code  = ct*16 + (l & 15);
    int dbase = ks*32 + (l >> 4)*8;
    const float* ep = emb + (size_t)code*DD + dbase;
    short8v h, lo;
#pragma unroll
    for (int j = 0; j < 8; ++j) {
        float v = ep[j];
        unsigned short hh = bf16_rne(v);
        h[j]  = (short)hh;
        lo[j] = (short)bf16_rne(v - bf16_tof(hh));
    }
    ((short8v*)ebh)[t] = h;
    ((short8v*)ebl)[t] = lo;
}

// ---------------------------------------------------------------------------
// Main: 256 pixels/block x 1024 codes via bf16 MFMA (3-pass hi/lo split),
// per-row top-2 tracking; ambiguous rows flagged for exact fp32 emulation.
__global__ __launch_bounds__(256, 2) void vq_main(
        const float* __restrict__ z, const short* __restrict__ ebh,
        const short* __restrict__ ebl, const float* __restrict__ e2,
        int* __restrict__ idx, int* __restrict__ list, int* __restrict__ cnt) {
    const int tid = threadIdx.x;
    const int w   = tid >> 6;            // wave 0..3: rows w*64..w*64+63
    const int l   = tid & 63;
    const int lr  = l & 15;              // row-in-tile (A) / col-in-tile (B,C)
    const int lg  = l >> 4;              // lane group
    const int b   = blockIdx.x >> 4;
    const int hw0 = (blockIdx.x & 15) * 256;
    const float* zb = z + (size_t)b*(DD*HWSZ) + hw0;

    // A-frags: rows = pixels. ah/al[rt][ks]; element j <-> d = ks*32+lg*8+j.
    short8v ah[4][2], al[4][2];
#pragma unroll
    for (int rt = 0; rt < 4; ++rt) {
#pragma unroll
        for (int ks = 0; ks < 2; ++ks) {
            int px = w*64 + rt*16 + lr;
            int dbase = ks*32 + lg*8;
#pragma unroll
            for (int j = 0; j < 8; ++j) {
                float v = zb[(size_t)(dbase + j)*HWSZ + px];
                unsigned short hh = bf16_rne(v);
                ah[rt][ks][j] = (short)hh;
                al[rt][ks][j] = (short)bf16_rne(v - bf16_tof(hh));
            }
        }
    }

    float best[4][4], best2[4][4];
    int   bib[4][4];
#pragma unroll
    for (int rt = 0; rt < 4; ++rt)
#pragma unroll
        for (int r = 0; r < 4; ++r) {
            best[rt][r] = 3.4e38f; best2[rt][r] = 3.4e38f; bib[rt][r] = 0;
        }

    const short8v* EBH = (const short8v*)ebh;
    const short8v* EBL = (const short8v*)ebl;

    // double-buffered B-frags (4 frags + e2 column entry)
    short8v bh0 = EBH[l],        bh1 = EBH[64 + l];
    short8v bl0 = EBL[l],        bl1 = EBL[64 + l];
    float   e2c = e2[lr];

#pragma unroll 1
    for (int ct = 0; ct < 64; ++ct) {
        int ctn = (ct + 1) & 63;                 // wraps harmlessly at end
        int s0  = ctn*128 + l;
        short8v nh0 = EBH[s0], nh1 = EBH[s0+64];
        short8v nl0 = EBL[s0], nl1 = EBL[s0+64];
        float   ne2 = e2[ctn*16 + lr];

        int kcol = ct*16 + lr;                   // this lane's code index
#pragma unroll
        for (int rt = 0; rt < 4; ++rt) {
            float4v acc = {0.f, 0.f, 0.f, 0.f};
            acc = __builtin_amdgcn_mfma_f32_16x16x32_bf16(ah[rt][0], bh0, acc, 0,0,0);
            acc = __builtin_amdgcn_mfma_f32_16x16x32_bf16(ah[rt][1], bh1, acc, 0,0,0);
            acc = __builtin_amdgcn_mfma_f32_16x16x32_bf16(ah[rt][0], bl0, acc, 0,0,0);
            acc = __builtin_amdgcn_mfma_f32_16x16x32_bf16(ah[rt][1], bl1, acc, 0,0,0);
            acc = __builtin_amdgcn_mfma_f32_16x16x32_bf16(al[rt][0], bh0, acc, 0,0,0);
            acc = __builtin_amdgcn_mfma_f32_16x16x32_bf16(al[rt][1], bh1, acc, 0,0,0);
#pragma unroll
            for (int r = 0; r < 4; ++r) {
                float s = __builtin_fmaf(-2.f, acc[r], e2c);  // score ~ B_k - z2
                bool lt = s < best[rt][r];
                best2[rt][r] = lt ? best[rt][r] : fminf(best2[rt][r], s);
                best[rt][r]  = fminf(best[rt][r], s);
                bib[rt][r]   = lt ? kcol : bib[rt][r];
            }
        }
        bh0 = nh0; bh1 = nh1; bl0 = nl0; bl1 = nl1; e2c = ne2;
    }

    // cross-lane top-2 merge over the 16 lanes sharing the same C rows
#pragma unroll
    for (int rt = 0; rt < 4; ++rt) {
#pragma unroll
        for (int r = 0; r < 4; ++r) {
            float b1 = best[rt][r], b2 = best2[rt][r];
            int   bi = bib[rt][r];
#pragma unroll
            for (int m = 1; m < 16; m <<= 1) {
                float ob1 = __shfl_xor(b1, m, 64);
                float ob2 = __shfl_xor(b2, m, 64);
                int   obi = __shfl_xor(bi, m, 64);
                float nb2 = fminf(fmaxf(b1, ob1), fminf(b2, ob2));
                bool take = (ob1 < b1) || (ob1 == b1 && obi < bi);
                b1 = fminf(b1, ob1);
                bi = take ? obi : bi;
                b2 = nb2;
            }
            if (lr == 0) {
                int row = hw0 + w*64 + rt*16 + lg*4 + r;   // C: row=(lg)*4+r
                int n   = b*HWSZ + row;
                idx[n] = bi;
                if (b2 - b1 <= BAND) {                     // ambiguous -> exact
                    int p = atomicAdd(cnt, 1);
                    list[p] = n;
                }
            }
        }
    }
}

// ---------------------------------------------------------------------------
// Exact fp32 emulation for flagged rows (bit-identical to the round-5 PASS):
// B_k = fl( fl(z2+e2k) - 2*dot ), dot = d-ascending fp32 FMA chain from 0.
// One wave per row; lane covers codes [l*16, l*16+16).
__global__ __launch_bounds__(256) void vq_exact(
        const float* __restrict__ z, const float* __restrict__ emb,
        const float* __restrict__ e2, const int* __restrict__ list,
        const int* __restrict__ cnt, int* __restrict__ idx) {
    __shared__ float zsh[4][64];
    const int wslot = threadIdx.x >> 6;
    const int l     = threadIdx.x & 63;
    const int wid   = (blockIdx.x * 256 + threadIdx.x) >> 6;
    const int nw    = (gridDim.x * 256) >> 6;
    const int C     = *cnt;

    for (int i = wid; i < C; i += nw) {
        int n  = list[i];
        int b  = n >> 12, hw = n & 4095;
        const float* zp = z + (size_t)b*(DD*HWSZ) + hw;
        zsh[wslot][l] = zp[(size_t)l * HWSZ];   // lane l loads z[d=l]

        float a[DD];
#pragma unroll
        for (int d = 0; d < DD; ++d) a[d] = zsh[wslot][d];
        float z2 = np_sumsq64(a);

        float bestv = 3.4e38f; int bi = 0;
#pragma unroll 1
        for (int j = 0; j < 16; ++j) {
            int k = l*16 + j;
            const float4* ep = reinterpret_cast<const float4*>(emb + (size_t)k*DD);
            float s = 0.f;
#pragma unroll
            for (int q = 0; q < 16; ++q) {
                float4 e  = ep[q];
                float4 zv = *reinterpret_cast<const float4*>(&zsh[wslot][4*q]);
                s = __builtin_fmaf(zv.x, e.x, s);
                s = __builtin_fmaf(zv.y, e.y, s);
                s = __builtin_fmaf(zv.z, e.z, s);
                s = __builtin_fmaf(zv.w, e.w, s);
            }
            float A  = z2 + e2[k];                       // fl(z2+e2k)
            float Bv = __builtin_fmaf(-2.f, s, A);       // fl(A-2*dot)
            if (Bv < bestv) { bestv = Bv; bi = k; }      // first-min (k asc)
        }
#pragma unroll
        for (int m = 1; m < 64; m <<= 1) {
            float ob = __shfl_xor(bestv, m, 64);
            int   oi = __shfl_xor(bi, m, 64);
            bool take = (ob < bestv) || (ob == bestv && oi < bi);
            bestv = take ? ob : bestv;
            bi    = take ? oi : bi;
        }
        if (l == 0) idx[n] = bi;
    }
}

// ---------------------------------------------------------------------------
// Epilogue: gather z_q, write z_q_st (+indices as float), partial loss sums.
__global__ __launch_bounds__(256) void vq_epilogue(
        const float* __restrict__ z, const float* __restrict__ emb,
        const int* __restrict__ idx, float* __restrict__ out,
        double* __restrict__ partial) {
    int n  = blockIdx.x * blockDim.x + threadIdx.x;
    int b  = n >> 12;
    int hw = n & 4095;
    const float* zp = z   + (size_t)b * (DD*HWSZ) + hw;
    float*       op = out + (size_t)b * (DD*HWSZ) + hw;
    int ki = idx[n];
    const float* ek = emb + (size_t)ki * DD;

    float lsum = 0.f;
#pragma unroll
    for (int d = 0; d < DD; ++d) {
        float e  = ek[d];
        float zv = zp[(size_t)d * HWSZ];
        op[(size_t)d * HWSZ] = e;            // z_q_st == z_q
        float df = e - zv;
        lsum = __builtin_fmaf(df, df, lsum);
    }
    out[IDX_OUT_OFF + n] = (float)ki;

    __shared__ double sred[256];
    sred[threadIdx.x] = (double)lsum;
    __syncthreads();
#pragma unroll
    for (int s = 128; s > 0; s >>= 1) {
        if (threadIdx.x < s) sred[threadIdx.x] += sred[threadIdx.x + s];
        __syncthreads();
    }
    if (threadIdx.x == 0) partial[blockIdx.x] = sred[0];
}

// ---------------------------------------------------------------------------
__global__ __launch_bounds__(256) void vq_finalize(
        const double* __restrict__ part, float* __restrict__ out) {
    __shared__ double sred[256];
    int t = threadIdx.x;
    sred[t] = part[t] + part[t + 256];       // 512 partials
    __syncthreads();
#pragma unroll
    for (int s = 128; s > 0; s >>= 1) {
        if (t < s) sred[t] += sred[t + s];
        __syncthreads();
    }
    if (t == 0) {
        double m = sred[0] / (double)NELEM;
        out[LOSS_OFF]     = (float)m;
        out[LOSS_OFF + 1] = (float)(0.25 * m);
    }
}

// ---------------------------------------------------------------------------
extern "C" void kernel_launch(void* const* d_in, const int* in_sizes, int n_in,
                              void* d_out, int out_size, void* d_ws, size_t ws_size,
                              hipStream_t stream) {
    const float* z   = (const float*)d_in[0];
    const float* emb = (const float*)d_in[1];
    float* out = (float*)d_out;
    char*  ws  = (char*)d_ws;

    float*  e2p  = (float*)(ws + WS_E2);
    short*  ebh  = (short*)(ws + WS_EBH);
    short*  ebl  = (short*)(ws + WS_EBL);
    int*    idxp = (int*)(ws + WS_IDX);
    int*    lst  = (int*)(ws + WS_LIST);
    int*    cntp = (int*)(ws + WS_CNT);
    double* part = (double*)(ws + WS_PART);

    hipMemsetAsync(cntp, 0, 4, stream);
    vq_e2       <<<KK/256,   256, 0, stream>>>(emb, e2p);
    vq_bfrag    <<<32,       256, 0, stream>>>(emb, ebh, ebl);
    vq_main     <<<NPIX/256, 256, 0, stream>>>(z, ebh, ebl, e2p, idxp, lst, cntp);
    vq_exact    <<<256,      256, 0, stream>>>(z, emb, e2p, lst, cntp, idxp);
    vq_epilogue <<<NPIX/256, 256, 0, stream>>>(z, emb, idxp, out, part);
    vq_finalize <<<1,        256, 0, stream>>>(part, out);
}

// Round 7
// 400.815 us; speedup vs baseline: 1.0455x; 1.0455x over previous
//
#include <hip/hip_runtime.h>

// Problem geometry (fixed by setup_inputs)
#define BB 32
#define DD 64
#define HWSZ 4096                  // H*W
#define KK 1024
#define NPIX (BB*HWSZ)             // 131072
#define NELEM (NPIX*DD)            // 8388608

// Output layout (concatenated float32)
#define IDX_OUT_OFF NELEM
#define LOSS_OFF (IDX_OUT_OFF + NPIX)

// Workspace layout (bytes)
#define WS_E2    0                        // 4 KB
#define WS_ET    (WS_E2 + 4096)           // 256 KB  eT[d][k]
#define WS_EBH   (WS_ET + DD*KK*4)        // 128 KB  B-frags hi
#define WS_EBL   (WS_EBH + KK*DD*2)       // 128 KB  B-frags lo
#define WS_IDX   (WS_EBL + KK*DD*2)       // 512 KB
#define WS_LIST  (WS_IDX + NPIX*4)        // 512 KB
#define WS_CNT   (WS_LIST + NPIX*4)       // 64 B
#define WS_PART  (WS_CNT + 64)            // 4 KB

// Ambiguity band (proven in round 6): covers ref's two magnitude-64 fp32
// roundings (<=3e-5 pairwise) + MFMA split error (<=1e-6), 4.7x margin.
#define BAND 1.5e-4f

typedef __attribute__((ext_vector_type(8))) short short8v;
typedef __attribute__((ext_vector_type(4))) float float4v;

__device__ __forceinline__ unsigned short bf16_rne(float f) {
    unsigned u = __float_as_uint(f);
    u += 0x7fffu + ((u >> 16) & 1u);
    return (unsigned short)(u >> 16);
}
__device__ __forceinline__ float bf16_tof(unsigned short h) {
    return __uint_as_float(((unsigned)h) << 16);
}

// numpy-style fp32 sum of 64 squares (squares rounded separately; no FMA).
__device__ __forceinline__ float np_sumsq64(const float* a) {
#pragma clang fp contract(off)
    float r0=0.f,r1=0.f,r2=0.f,r3=0.f,r4=0.f,r5=0.f,r6=0.f,r7=0.f;
#pragma unroll
    for (int i = 0; i < 64; i += 8) {
        r0 += a[i+0]*a[i+0]; r1 += a[i+1]*a[i+1];
        r2 += a[i+2]*a[i+2]; r3 += a[i+3]*a[i+3];
        r4 += a[i+4]*a[i+4]; r5 += a[i+5]*a[i+5];
        r6 += a[i+6]*a[i+6]; r7 += a[i+7]*a[i+7];
    }
    return ((r0+r1)+(r2+r3))+((r4+r5)+(r6+r7));
}

// ---------------------------------------------------------------------------
__global__ __launch_bounds__(256) void vq_e2(const float* __restrict__ emb,
                                             float* __restrict__ e2) {
    int k = blockIdx.x * blockDim.x + threadIdx.x;
    float ek[DD];
    const float4* p = reinterpret_cast<const float4*>(emb + (size_t)k * DD);
#pragma unroll
    for (int q = 0; q < 16; ++q) {
        float4 v = p[q];
        ek[4*q+0]=v.x; ek[4*q+1]=v.y; ek[4*q+2]=v.z; ek[4*q+3]=v.w;
    }
    e2[k] = np_sumsq64(ek);
}

// ---------------------------------------------------------------------------
__global__ __launch_bounds__(256) void vq_transpose(const float* __restrict__ emb,
                                                    float* __restrict__ eT) {
    int i = blockIdx.x * blockDim.x + threadIdx.x;   // over 64*1024
    int d = i >> 10;
    int k = i & 1023;
    eT[i] = emb[(size_t)k * DD + d];
}

// ---------------------------------------------------------------------------
// B-fragments of the hi/lo bf16 split of emb^T (slot=ct*2+ks; see vq_main).
__global__ __launch_bounds__(256) void vq_bfrag(const float* __restrict__ emb,
                                                short* __restrict__ ebh,
                                                short* __restrict__ ebl) {
    int t    = blockIdx.x * 256 + threadIdx.x;   // 8192 = 128 slots * 64 lanes
    int l    = t & 63;
    int slot = t >> 6;
    int ct = slot >> 1, ks = slot & 1;
    int code  = ct*16 + (l & 15);
    int dbase = ks*32 + (l >> 4)*8;
    const float* ep = emb + (size_t)code*DD + dbase;
    short8v h, lo;
#pragma unroll
    for (int j = 0; j < 8; ++j) {
        float v = ep[j];
        unsigned short hh = bf16_rne(v);
        h[j]  = (short)hh;
        lo[j] = (short)bf16_rne(v - bf16_tof(hh));
    }
    ((short8v*)ebh)[t] = h;
    ((short8v*)ebl)[t] = lo;
}

// ---------------------------------------------------------------------------
// Main: 256 px/block x 1024 codes via bf16 MFMA (3-pass hi/lo), top-2 + band.
// z tile staged through LDS (coalesced) before A-fragment build.
__global__ __launch_bounds__(256, 2) void vq_main(
        const float* __restrict__ z, const short* __restrict__ ebh,
        const short* __restrict__ ebl, const float* __restrict__ e2,
        int* __restrict__ idx, int* __restrict__ list, int* __restrict__ cnt) {
    __shared__ float zsh[DD * 256];      // 64 KB, [d][px]
    const int tid = threadIdx.x;
    const int w   = tid >> 6;
    const int l   = tid & 63;
    const int lr  = l & 15;
    const int lg  = l >> 4;
    const int b   = blockIdx.x >> 4;
    const int hw0 = (blockIdx.x & 15) * 256;
    const float* zb = z + (size_t)b*(DD*HWSZ) + hw0;

    // coalesced stage: global [d][4096] -> LDS [d][256]
#pragma unroll 8
    for (int d = 0; d < DD; ++d)
        zsh[d * 256 + tid] = zb[(size_t)d * HWSZ + tid];
    __syncthreads();

    // A-frags from LDS. ah/al[rt][ks]; elem j <-> d = ks*32+lg*8+j.
    short8v ah[4][2], al[4][2];
#pragma unroll
    for (int rt = 0; rt < 4; ++rt) {
#pragma unroll
        for (int ks = 0; ks < 2; ++ks) {
            int px = w*64 + rt*16 + lr;
            int dbase = ks*32 + lg*8;
#pragma unroll
            for (int j = 0; j < 8; ++j) {
                float v = zsh[(dbase + j)*256 + px];
                unsigned short hh = bf16_rne(v);
                ah[rt][ks][j] = (short)hh;
                al[rt][ks][j] = (short)bf16_rne(v - bf16_tof(hh));
            }
        }
    }

    float best[4][4], best2[4][4];
    int   bib[4][4];
#pragma unroll
    for (int rt = 0; rt < 4; ++rt)
#pragma unroll
        for (int r = 0; r < 4; ++r) {
            best[rt][r] = 3.4e38f; best2[rt][r] = 3.4e38f; bib[rt][r] = 0;
        }

    const short8v* EBH = (const short8v*)ebh;
    const short8v* EBL = (const short8v*)ebl;

    short8v bh0 = EBH[l],  bh1 = EBH[64 + l];
    short8v bl0 = EBL[l],  bl1 = EBL[64 + l];
    float   e2c = e2[lr];

#pragma unroll 1
    for (int ct = 0; ct < 64; ++ct) {
        int ctn = (ct + 1) & 63;
        int s0  = ctn*128 + l;
        short8v nh0 = EBH[s0], nh1 = EBH[s0+64];
        short8v nl0 = EBL[s0], nl1 = EBL[s0+64];
        float   ne2 = e2[ctn*16 + lr];

        int kcol = ct*16 + lr;
#pragma unroll
        for (int rt = 0; rt < 4; ++rt) {
            float4v acc = {0.f, 0.f, 0.f, 0.f};
            acc = __builtin_amdgcn_mfma_f32_16x16x32_bf16(ah[rt][0], bh0, acc, 0,0,0);
            acc = __builtin_amdgcn_mfma_f32_16x16x32_bf16(ah[rt][1], bh1, acc, 0,0,0);
            acc = __builtin_amdgcn_mfma_f32_16x16x32_bf16(ah[rt][0], bl0, acc, 0,0,0);
            acc = __builtin_amdgcn_mfma_f32_16x16x32_bf16(ah[rt][1], bl1, acc, 0,0,0);
            acc = __builtin_amdgcn_mfma_f32_16x16x32_bf16(al[rt][0], bh0, acc, 0,0,0);
            acc = __builtin_amdgcn_mfma_f32_16x16x32_bf16(al[rt][1], bh1, acc, 0,0,0);
#pragma unroll
            for (int r = 0; r < 4; ++r) {
                float s = __builtin_fmaf(-2.f, acc[r], e2c);
                bool lt = s < best[rt][r];
                best2[rt][r] = lt ? best[rt][r] : fminf(best2[rt][r], s);
                best[rt][r]  = fminf(best[rt][r], s);
                bib[rt][r]   = lt ? kcol : bib[rt][r];
            }
        }
        bh0 = nh0; bh1 = nh1; bl0 = nl0; bl1 = nl1; e2c = ne2;
    }

#pragma unroll
    for (int rt = 0; rt < 4; ++rt) {
#pragma unroll
        for (int r = 0; r < 4; ++r) {
            float b1 = best[rt][r], b2 = best2[rt][r];
            int   bi = bib[rt][r];
#pragma unroll
            for (int m = 1; m < 16; m <<= 1) {
                float ob1 = __shfl_xor(b1, m, 64);
                float ob2 = __shfl_xor(b2, m, 64);
                int   obi = __shfl_xor(bi, m, 64);
                float nb2 = fminf(fmaxf(b1, ob1), fminf(b2, ob2));
                bool take = (ob1 < b1) || (ob1 == b1 && obi < bi);
                b1 = fminf(b1, ob1);
                bi = take ? obi : bi;
                b2 = nb2;
            }
            if (lr == 0) {
                int row = hw0 + w*64 + rt*16 + lg*4 + r;   // C: row=(l>>4)*4+r
                int n   = b*HWSZ + row;
                idx[n] = bi;
                if (b2 - b1 <= BAND) {
                    int p = atomicAdd(cnt, 1);
                    list[p] = n;
                }
            }
        }
    }
}

// ---------------------------------------------------------------------------
// Exact fp32 pass, round-5 structure: block = 64 flagged rows x 4 k-splits.
// Wave s scans k in [s*256,(s+1)*256) for 64 rows (one per lane) -> eT/e2
// reads are wave-uniform scalar loads. Bit-identical chain to round-5 PASS.
__global__ __launch_bounds__(256, 2) void vq_exact2(
        const float* __restrict__ z, const float* __restrict__ eT,
        const float* __restrict__ e2, const int* __restrict__ list,
        const int* __restrict__ cnt, int* __restrict__ idx) {
    __shared__ float zsh[DD * 64];       // [d][row], 16 KB
    __shared__ float sb[4][64];
    __shared__ int   si[4][64];

    const int tid  = threadIdx.x;
    const int lane = tid & 63;           // row slot
    const int s    = tid >> 6;           // k-split (wave id)
    const int C    = *cnt;

    for (int chunk = blockIdx.x; chunk*64 < C; chunk += gridDim.x) {
        const int base  = chunk * 64;
        const int irow  = base + lane;
        const int n     = list[irow < C ? irow : (C-1)];
        const int bq    = n >> 12;
        const int hw    = n & 4095;
        const float* zp = z + (size_t)bq*(DD*HWSZ) + hw;

        // stage 64 rows x 64 d (each thread: its lane-row, 16 d values)
#pragma unroll
        for (int it = 0; it < 16; ++it) {
            int d = s + it*4;
            zsh[d*64 + lane] = zp[(size_t)d * HWSZ];
        }
        __syncthreads();

        float a[DD];
#pragma unroll
        for (int d = 0; d < DD; ++d) a[d] = zsh[d*64 + lane];
        const float z2 = np_sumsq64(a);

        float bestv = 3.4e38f; int bi = 0;
#pragma unroll 1
        for (int g = 0; g < 16; ++g) {
            int k0 = s*256 + g*16;
            float acc[16];
#pragma unroll
            for (int j = 0; j < 16; ++j) acc[j] = 0.f;
#pragma unroll
            for (int d = 0; d < DD; ++d) {
                const float* ed = eT + d*KK + k0;        // wave-uniform
                float zd = a[d];
#pragma unroll
                for (int j = 0; j < 16; ++j)
                    acc[j] = __builtin_fmaf(zd, ed[j], acc[j]);
            }
            {
#pragma clang fp contract(off)
#pragma unroll
                for (int j = 0; j < 16; ++j) {
                    float A  = z2 + e2[k0 + j];                  // fl(z2+e2k)
                    float Bv = __builtin_fmaf(-2.f, acc[j], A);  // fl(A-2dot)
                    if (Bv < bestv) { bestv = Bv; bi = k0 + j; } // first-min
                }
            }
        }

        sb[s][lane] = bestv;
        si[s][lane] = bi;
        __syncthreads();

        if (tid < 64 && base + tid < C) {
            float bv = sb[0][tid]; int bk = si[0][tid];
#pragma unroll
            for (int q = 1; q < 4; ++q) {            // ascending-k splits
                float ov = sb[q][tid]; int ok = si[q][tid];
                if (ov < bv) { bv = ov; bk = ok; }   // strict: first-min kept
            }
            idx[list[base + tid]] = bk;
        }
        __syncthreads();
    }
}

// ---------------------------------------------------------------------------
__global__ __launch_bounds__(256) void vq_epilogue(
        const float* __restrict__ z, const float* __restrict__ emb,
        const int* __restrict__ idx, float* __restrict__ out,
        double* __restrict__ partial) {
    int n  = blockIdx.x * blockDim.x + threadIdx.x;
    int b  = n >> 12;
    int hw = n & 4095;
    const float* zp = z   + (size_t)b * (DD*HWSZ) + hw;
    float*       op = out + (size_t)b * (DD*HWSZ) + hw;
    int ki = idx[n];
    const float* ek = emb + (size_t)ki * DD;

    float lsum = 0.f;
#pragma unroll
    for (int d = 0; d < DD; ++d) {
        float e  = ek[d];
        float zv = zp[(size_t)d * HWSZ];
        op[(size_t)d * HWSZ] = e;            // z_q_st == z_q
        float df = e - zv;
        lsum = __builtin_fmaf(df, df, lsum);
    }
    out[IDX_OUT_OFF + n] = (float)ki;

    __shared__ double sred[256];
    sred[threadIdx.x] = (double)lsum;
    __syncthreads();
#pragma unroll
    for (int sdown = 128; sdown > 0; sdown >>= 1) {
        if (threadIdx.x < sdown) sred[threadIdx.x] += sred[threadIdx.x + sdown];
        __syncthreads();
    }
    if (threadIdx.x == 0) partial[blockIdx.x] = sred[0];
}

// ---------------------------------------------------------------------------
__global__ __launch_bounds__(256) void vq_finalize(
        const double* __restrict__ part, float* __restrict__ out) {
    __shared__ double sred[256];
    int t = threadIdx.x;
    sred[t] = part[t] + part[t + 256];       // 512 partials
    __syncthreads();
#pragma unroll
    for (int sdown = 128; sdown > 0; sdown >>= 1) {
        if (t < sdown) sred[t] += sred[t + sdown];
        __syncthreads();
    }
    if (t == 0) {
        double m = sred[0] / (double)NELEM;
        out[LOSS_OFF]     = (float)m;
        out[LOSS_OFF + 1] = (float)(0.25 * m);
    }
}

// ---------------------------------------------------------------------------
extern "C" void kernel_launch(void* const* d_in, const int* in_sizes, int n_in,
                              void* d_out, int out_size, void* d_ws, size_t ws_size,
                              hipStream_t stream) {
    const float* z   = (const float*)d_in[0];
    const float* emb = (const float*)d_in[1];
    float* out = (float*)d_out;
    char*  ws  = (char*)d_ws;

    float*  e2p  = (float*)(ws + WS_E2);
    float*  eT   = (float*)(ws + WS_ET);
    short*  ebh  = (short*)(ws + WS_EBH);
    short*  ebl  = (short*)(ws + WS_EBL);
    int*    idxp = (int*)(ws + WS_IDX);
    int*    lst  = (int*)(ws + WS_LIST);
    int*    cntp = (int*)(ws + WS_CNT);
    double* part = (double*)(ws + WS_PART);

    hipMemsetAsync(cntp, 0, 4, stream);
    vq_e2        <<<KK/256,      256, 0, stream>>>(emb, e2p);
    vq_transpose <<<(DD*KK)/256, 256, 0, stream>>>(emb, eT);
    vq_bfrag     <<<32,          256, 0, stream>>>(emb, ebh, ebl);
    vq_main      <<<NPIX/256,    256, 0, stream>>>(z, ebh, ebl, e2p, idxp, lst, cntp);
    vq_exact2    <<<512,         256, 0, stream>>>(z, eT, e2p, lst, cntp, idxp);
    vq_epilogue  <<<NPIX/256,    256, 0, stream>>>(z, emb, idxp, out, part);
    vq_finalize  <<<1,           256, 0, stream>>>(part, out);
}